// Round 15
// baseline (1678.368 us; speedup 1.0000x reference)
//
#include <hip/hip_runtime.h>
#include <hip/hip_fp16.h>
#include <stdint.h>

#define T_STEPS 1024
#define HDIM    128
#define NT      512

// K-sliced, single-barrier pipelined design (R15 = R14 with the MAC
// instruction swapped: v_dot2_f32_f16 -> v_pk_fma_f16 + dot2-fold):
//   wave w = tid>>6 (0..7), lane l = tid&63
//   slice   s = l & 3        -> h columns [32s, 32s+32)
//   element e = 16w + (l>>2) (0..127)
// Iteration k fuses: gates1(k)   = W_hh1*h1(k-1)            (+ x(k), bias)
//                    gates2(k-1) = W_ih2*h1(k-1) + W_hh2*h2(k-2)
// One fused MAC block, two epilogues, ONE barrier.
//
// R14 issue accounting (VALUBusy 70.8% x 3850 cyc/step = 2726 cyc issue;
// epilogue ~1200): only consistent if v_dot2_f32_f16 issues at HALF rate
// (4 cyc) -> dots = 1536 cyc/SIMD/step, the dominant term. v_pk_fma_f16
// is a standard VOP3P packed op expected at full rate (2 cyc, like
// v_fma_f32 per m07). PK8 = 8 pk_fma (two 8-term f16 chains in a packed
// acc) + 1 dot2((1,1)) fold into f32: 20 cyc vs DOT8's 32. Saves ~576
// cyc/SIMD/step (~15%) if full-rate; ~neutral if pk_fma is also 4 cyc.
// Precision: 8-term f16 chains add ~1e-4 gate noise, damped by the
// recurrence; expect absmax <= ~5e-4 (revert if > 1e-3).

typedef _Float16 v2h __attribute__((ext_vector_type(2)));
union HU { uint32_t u; v2h v; };

#define SCL  1.44269504088896340736f   // log2(e)
#define K2C  2.88538008177792681472f   // 2*log2(e)
#define ONES 0x3C003C00u               // f16 (1.0, 1.0)

__device__ __forceinline__ float dot2h(uint32_t a, uint32_t b, float c) {
    HU ua, ub; ua.u = a; ub.u = b;
    return __builtin_amdgcn_fdot2(ua.v, ub.v, c, false);  // v_dot2_f32_f16
}
// packed f16 FMA: d = a*b + c  (v_pk_fma_f16, full-rate VOP3P)
__device__ __forceinline__ v2h pkfma(uint32_t a, uint32_t b, v2h c) {
    HU ua, ub; ua.u = a; ub.u = b;
    return __builtin_elementwise_fma(ua.v, ub.v, c);
}
__device__ __forceinline__ uint32_t packh2s(float2 e) {   // pre-scaled pack
    return (uint32_t)__half_as_ushort(__float2half_rn(e.x * SCL)) |
           ((uint32_t)__half_as_ushort(__float2half_rn(e.y * SCL)) << 16);
}
__device__ __forceinline__ uint16_t f2h(float f) {
    return __half_as_ushort(__float2half_rn(f));
}
// Pre-scaled activations: input a2 = a*log2e.
__device__ __forceinline__ float act2(float a2, float m) {
    return 1.0f - m * __builtin_amdgcn_rcpf(
        __builtin_amdgcn_exp2f(m * a2) + 1.0f);
}
__device__ __forceinline__ float tanhc(float c) {
    return 1.0f - 2.0f * __builtin_amdgcn_rcpf(
        __builtin_amdgcn_exp2f(K2C * c) + 1.0f);
}
// reduce over the 4 slice-lanes (lane bits 0..1): two DPP quad-perm adds.
__device__ __forceinline__ float red2(float v) {
    int iv = __float_as_int(v);
    v += __int_as_float(__builtin_amdgcn_update_dpp(0, iv, 0xB1, 0xF, 0xF, true)); // xor1
    iv = __float_as_int(v);
    v += __int_as_float(__builtin_amdgcn_update_dpp(0, iv, 0x4E, 0xF, 0xF, true)); // xor2
    return v;
}

#define SB() __builtin_amdgcn_sched_barrier(0)
#define PIN4(W) asm volatile("" : "+v"(W.x), "+v"(W.y), "+v"(W.z), "+v"(W.w))

// pack 32 consecutive floats at P into 4 uint4 of pre-scaled f16 pairs
#define SETW16(Wa, Wb, Wc, Wd, P) do { const float2* _r = (const float2*)(P); \
    Wa = make_uint4(packh2s(_r[0]),  packh2s(_r[1]),                       \
                    packh2s(_r[2]),  packh2s(_r[3]));                      \
    Wb = make_uint4(packh2s(_r[4]),  packh2s(_r[5]),                       \
                    packh2s(_r[6]),  packh2s(_r[7]));                      \
    Wc = make_uint4(packh2s(_r[8]),  packh2s(_r[9]),                       \
                    packh2s(_r[10]), packh2s(_r[11]));                     \
    Wd = make_uint4(packh2s(_r[12]), packh2s(_r[13]),                      \
                    packh2s(_r[14]), packh2s(_r[15])); } while (0)

// row pack + immediate pin + scheduling fence: caps init pressure spike.
#define ROW(Wa, Wb, Wc, Wd, P) do {                                        \
    SETW16(Wa, Wb, Wc, Wd, P);                                             \
    PIN4(Wa); PIN4(Wb); PIN4(Wc); PIN4(Wd); SB(); } while (0)

// 16 MACs: one weight pair (2 uint4 = 16 cols) vs h pair, via 8 full-rate
// v_pk_fma_f16 (two independent 8-term f16 chains) + 1 dot2 fold to f32.
#define PK8(Wa, Wb, H0, H1, facc) do {                                     \
    HU _z; _z.u = 0u; v2h _p = _z.v;                                       \
    _p = pkfma(Wa.x, H0.x, _p); _p = pkfma(Wa.y, H0.y, _p);                \
    _p = pkfma(Wa.z, H0.z, _p); _p = pkfma(Wa.w, H0.w, _p);                \
    _p = pkfma(Wb.x, H1.x, _p); _p = pkfma(Wb.y, H1.y, _p);                \
    _p = pkfma(Wb.z, H1.z, _p); _p = pkfma(Wb.w, H1.w, _p);                \
    HU _o; _o.v = _p; facc = dot2h(_o.u, ONES, facc); } while (0)

__global__ __launch_bounds__(NT)
__attribute__((amdgpu_waves_per_eu(2, 2)))
void lstm_persistent(
    const float* __restrict__ x,
    const float* __restrict__ W_ih1, const float* __restrict__ W_hh1,
    const float* __restrict__ b_ih1, const float* __restrict__ b_hh1,
    const float* __restrict__ W_ih2, const float* __restrict__ W_hh2,
    const float* __restrict__ b_ih2, const float* __restrict__ b_hh2,
    const float* __restrict__ W_out, const float* __restrict__ b_out,
    float* __restrict__ out)
{
    const int b   = blockIdx.x;
    const int tid = threadIdx.x;
    const int w   = tid >> 6;
    const int l   = tid & 63;
    const int s   = l & 3;
    const int e   = (w << 4) | (l >> 2);
    const int co  = s << 5;                       // column offset (floats)

    __shared__ __align__(16) uint32_t h1p[2][HDIM / 2];   // h1 f16 pairs, dbuf
    __shared__ __align__(16) uint32_t h2p[2][HDIM / 2];   // h2 f16 pairs, dbuf
    __shared__ float pbuf[2][8];                  // per-wave out partials, dbuf

    // ---- one-time: weight slices -> 48 named uint4 (192 dwords), fenced
    uint4 m1_00,m1_01,m1_02,m1_03, m1_10,m1_11,m1_12,m1_13;   // W_hh1
    uint4 m1_20,m1_21,m1_22,m1_23, m1_30,m1_31,m1_32,m1_33;
    uint4 m2_00,m2_01,m2_02,m2_03, m2_10,m2_11,m2_12,m2_13;   // W_ih2
    uint4 m2_20,m2_21,m2_22,m2_23, m2_30,m2_31,m2_32,m2_33;
    uint4 m3_00,m3_01,m3_02,m3_03, m3_10,m3_11,m3_12,m3_13;   // W_hh2
    uint4 m3_20,m3_21,m3_22,m3_23, m3_30,m3_31,m3_32,m3_33;
    {
        const float* p = W_hh1 + e * HDIM + co;
        ROW(m1_00,m1_01,m1_02,m1_03, p);
        ROW(m1_10,m1_11,m1_12,m1_13, p + 128 * HDIM);
        ROW(m1_20,m1_21,m1_22,m1_23, p + 256 * HDIM);
        ROW(m1_30,m1_31,m1_32,m1_33, p + 384 * HDIM);
        p = W_ih2 + e * HDIM + co;
        ROW(m2_00,m2_01,m2_02,m2_03, p);
        ROW(m2_10,m2_11,m2_12,m2_13, p + 128 * HDIM);
        ROW(m2_20,m2_21,m2_22,m2_23, p + 256 * HDIM);
        ROW(m2_30,m2_31,m2_32,m2_33, p + 384 * HDIM);
        p = W_hh2 + e * HDIM + co;
        ROW(m3_00,m3_01,m3_02,m3_03, p);
        ROW(m3_10,m3_11,m3_12,m3_13, p + 128 * HDIM);
        ROW(m3_20,m3_21,m3_22,m3_23, p + 256 * HDIM);
        ROW(m3_30,m3_31,m3_32,m3_33, p + 384 * HDIM);
    }

    // ---- one-time: ALL biases / x-weights pre-scaled by log2e, in regs
    const float b1i = (b_ih1[e]       + b_hh1[e])       * SCL;
    const float b1f = (b_ih1[e + 128] + b_hh1[e + 128]) * SCL;
    const float b1g = (b_ih1[e + 256] + b_hh1[e + 256]) * SCL;
    const float b1o = (b_ih1[e + 384] + b_hh1[e + 384]) * SCL;
    const float wxi = W_ih1[e]       * SCL, wxf = W_ih1[e + 128] * SCL;
    const float wxg = W_ih1[e + 256] * SCL, wxo = W_ih1[e + 384] * SCL;
    const float b2i = (b_ih2[e]       + b_hh2[e])       * SCL;
    const float b2f = (b_ih2[e + 128] + b_hh2[e + 128]) * SCL;
    const float b2g = (b_ih2[e + 256] + b_hh2[e + 256]) * SCL;
    const float b2o = (b_ih2[e + 384] + b_hh2[e + 384]) * SCL;
    const float wo = (s == 0) ? W_out[e] : 0.0f;
    const float bo = b_out[0];

    float c1 = 0.f, c2 = 0.f;                      // replicated across 4 lanes

    if (tid < HDIM / 2) {
        h1p[0][tid] = 0u; h1p[1][tid] = 0u;        // h1(-1) = h2(-1) = 0
        h2p[0][tid] = 0u; h2p[1][tid] = 0u;
    }
    __syncthreads();

    const float* xb = x + b * T_STEPS;
    float*       ob = out + b * T_STEPS;
    float x_cur = xb[0];

    // Iteration k (k = 0..T): computes h1(k) and h2(k-1)/out(k-1).
    for (int k = 0; k <= T_STEPS; ++k) {
        const int rb = k & 1, wbuf = rb ^ 1;
        float x_nxt = xb[(k + 1 < T_STEPS) ? (k + 1) : (T_STEPS - 1)];

        // ---- phase 1: h1 fragments, then m1 + m2 MACs (both consume h1).
        const uint4* H1 = (const uint4*)h1p[rb];
        uint4 Ha0 = H1[4*s+0], Ha1 = H1[4*s+1];   // h1 cols [co, co+16)
        uint4 Hb0 = H1[4*s+2], Hb1 = H1[4*s+3];   // h1 cols [co+16, co+32)
        float a0=0.f,a1=0.f,a2=0.f,a3=0.f, q0=0.f,q1=0.f,q2=0.f,q3=0.f;
        PK8(m1_00,m1_01, Ha0,Ha1, a0); PK8(m1_10,m1_11, Ha0,Ha1, a1);
        PK8(m1_20,m1_21, Ha0,Ha1, a2); PK8(m1_30,m1_31, Ha0,Ha1, a3);
        PK8(m1_02,m1_03, Hb0,Hb1, a0); PK8(m1_12,m1_13, Hb0,Hb1, a1);
        PK8(m1_22,m1_23, Hb0,Hb1, a2); PK8(m1_32,m1_33, Hb0,Hb1, a3);
        PK8(m2_00,m2_01, Ha0,Ha1, q0); PK8(m2_10,m2_11, Ha0,Ha1, q1);
        PK8(m2_20,m2_21, Ha0,Ha1, q2); PK8(m2_30,m2_31, Ha0,Ha1, q3);
        PK8(m2_02,m2_03, Hb0,Hb1, q0); PK8(m2_12,m2_13, Hb0,Hb1, q1);
        PK8(m2_22,m2_23, Hb0,Hb1, q2); PK8(m2_32,m2_33, Hb0,Hb1, q3);

        // ---- phase 2: issue h2 reads; latency filled by out-store + epi1.
        const uint4* H2 = (const uint4*)h2p[rb];
        uint4 Hc0 = H2[4*s+0], Hc1 = H2[4*s+1];
        uint4 Hd0 = H2[4*s+2], Hd1 = H2[4*s+3];

        // ---- store out(k-2): independent work under the h2 lgkm wait
        if (k >= 2 && tid < 8) {
            float ssum = pbuf[wbuf][tid];
            ssum += __shfl_xor(ssum, 1, 64);
            ssum += __shfl_xor(ssum, 2, 64);
            ssum += __shfl_xor(ssum, 4, 64);
            if (tid == 0) ob[k - 2] = ssum + bo;
        }

        // ---- epilogue 1: h1(k) — pre-scaled domain, raw exp2 activations
        a0 = red2(a0); a1 = red2(a1); a2 = red2(a2); a3 = red2(a3);
        float gi = act2(a0 + fmaf(x_cur, wxi, b1i), 1.0f);
        float gf = act2(a1 + fmaf(x_cur, wxf, b1f), 1.0f);
        float gg = act2(a2 + fmaf(x_cur, wxg, b1g), 2.0f);
        float go = act2(a3 + fmaf(x_cur, wxo, b1o), 1.0f);
        c1 = fmaf(gf, c1, gi * gg);
        float h1v = go * tanhc(c1);
        if (s == 0) ((uint16_t*)h1p[wbuf])[e] = f2h(h1v);

        // ---- phase 3: m3 MACs (h2 x W_hh2)
        PK8(m3_00,m3_01, Hc0,Hc1, q0); PK8(m3_10,m3_11, Hc0,Hc1, q1);
        PK8(m3_20,m3_21, Hc0,Hc1, q2); PK8(m3_30,m3_31, Hc0,Hc1, q3);
        PK8(m3_02,m3_03, Hd0,Hd1, q0); PK8(m3_12,m3_13, Hd0,Hd1, q1);
        PK8(m3_22,m3_23, Hd0,Hd1, q2); PK8(m3_32,m3_33, Hd0,Hd1, q3);

        // ---- epilogue 2: h2(k-1) + out(k-1) partial (skip at k=0)
        if (k > 0) {
            q0 = red2(q0); q1 = red2(q1); q2 = red2(q2); q3 = red2(q3);
            float hi = act2(q0 + b2i, 1.0f);
            float hf = act2(q1 + b2f, 1.0f);
            float hg = act2(q2 + b2g, 2.0f);
            float ho = act2(q3 + b2o, 1.0f);
            c2 = fmaf(hf, c2, hi * hg);
            float h2v = ho * tanhc(c2);
            if (s == 0) ((uint16_t*)h2p[wbuf])[e] = f2h(h2v);
            float part = wo * h2v;                 // wo==0 on s!=0 lanes
            part += __shfl_xor(part, 4,  64);
            part += __shfl_xor(part, 8,  64);
            part += __shfl_xor(part, 16, 64);
            part += __shfl_xor(part, 32, 64);
            if (l == 0) pbuf[rb][w] = part;
        }
        __syncthreads();   // single barrier: publish h1(k), h2(k-1), partials
        x_cur = x_nxt;
    }

    // ---- drain: out(T-1) partials were published at k=T (parity T&1)
    if (tid < 8) {
        float ssum = pbuf[T_STEPS & 1][tid];
        ssum += __shfl_xor(ssum, 1, 64);
        ssum += __shfl_xor(ssum, 2, 64);
        ssum += __shfl_xor(ssum, 4, 64);
        if (tid == 0) ob[T_STEPS - 1] = ssum + bo;
    }
}

extern "C" void kernel_launch(void* const* d_in, const int* in_sizes, int n_in,
                              void* d_out, int out_size, void* d_ws, size_t ws_size,
                              hipStream_t stream) {
    const float* x     = (const float*)d_in[0];
    const float* W_ih1 = (const float*)d_in[1];
    const float* W_hh1 = (const float*)d_in[2];
    const float* b_ih1 = (const float*)d_in[3];
    const float* b_hh1 = (const float*)d_in[4];
    const float* W_ih2 = (const float*)d_in[5];
    const float* W_hh2 = (const float*)d_in[6];
    const float* b_ih2 = (const float*)d_in[7];
    const float* b_hh2 = (const float*)d_in[8];
    const float* W_out = (const float*)d_in[9];
    const float* b_out = (const float*)d_in[10];
    float* out = (float*)d_out;

    const int B = in_sizes[0] / T_STEPS;   // 256
    hipLaunchKernelGGL(lstm_persistent, dim3(B), dim3(NT), 0, stream,
                       x, W_ih1, W_hh1, b_ih1, b_hh1,
                       W_ih2, W_hh2, b_ih2, b_hh2, W_out, b_out, out);
}